// Round 6
// baseline (185.278 us; speedup 1.0000x reference)
//
#include <hip/hip_runtime.h>
#include <math.h>

// ---------------------------------------------------------------------------
// PreLossSampler (N=1024):
//   out = [reg_valid | labels | max_overlaps | gt_assignment]  (4096 float32)
//
// Pipeline:
//   prep2    : reg_valid, labels, bitonic argsort(-labels), gather sorted gt,
//              circles, init sup/rowmax/cnt.
//   cand3(A) : gt x gt (sorted, j>i) circle-reject -> listA (one wave/block,
//              wave-private LDS buffer, one global atomicAdd per block).
//   evalA    : exact rotated-IoU on listA -> suppression bits (atomicOr).
//   nms_seq5 : greedy NMS, one wave; LDS-broadcast word + VALU cndmask chain,
//              register prefetch of next word-block's rows.
//   cand3(B) : pred x gt, sampled[j]-filtered circle test -> listB.
//   evalB    : exact IoU3D on listB; packed (iou, first-idx) u64 atomicMax.
//   fin      : unpack rowmax -> out[2], out[3].
//
// The polygon clip is scratch-free: every local array is <= 96 bytes
// (empirically the promote-alloca limit on this toolchain; 128 B+ arrays
// were left in scratch -> 122 us cold dispatch in round 5). Ordering is
// rank-based: stable-argsort ranks from 276 pairwise key compares, then
// position-order streaming reconstruction feeding the exact same masked
// sequential shoelace that validated at absmax 0.0.
// ---------------------------------------------------------------------------

#define NB 1024
#define CAP 131072u

typedef unsigned long long u64;

__device__ __forceinline__ bool pt_in_box(float px, float py,
        float bx, float by, float bdx, float bdy, float cs, float sn) {
    float dx = px - bx, dy = py - by;
    float lx = dx * cs + dy * sn;
    float ly = dy * cs - dx * sn;
    return (fabsf(lx) <= bdx * 0.5f + 1e-5f) && (fabsf(ly) <= bdy * 0.5f + 1e-5f);
}

// total-order sortable bits of a float (with -0 canonicalized via +0.0f)
__device__ __forceinline__ unsigned sortbits(float f) {
    unsigned u = __float_as_uint(f + 0.0f);
    return (u & 0x80000000u) ? ~u : (u | 0x80000000u);
}

// Rotated-rectangle intersection area; reference-exact op order; all arrays
// <= 96 B and statically indexed (register-resident, zero scratch).
__device__ float rect_inter_area(
        float ax, float ay, float adx, float ady, float ar,
        float bx, float by, float bdx, float bdy, float br) {
    // Circle reject (value-preserving: rejected pairs have k=0 -> area 0).
    float dcx = ax - bx, dcy = ay - by;
    float ra = 0.5f * sqrtf(adx * adx + ady * ady);
    float rb = 0.5f * sqrtf(bdx * bdx + bdy * bdy);
    float lim = ra + rb + 1e-3f;
    if (dcx * dcx + dcy * dcy > lim * lim) return 0.0f;

    float csa = cosf(ar), sna = sinf(ar);
    float csb = cosf(br), snb = sinf(br);
    float cax[4], cay[4], cbx[4], cby[4];
    const float SX[4] = {0.5f, 0.5f, -0.5f, -0.5f};
    const float SY[4] = {0.5f, -0.5f, -0.5f, 0.5f};
#pragma unroll
    for (int i = 0; i < 4; ++i) {
        float lx = SX[i] * adx, ly = SY[i] * ady;
        cax[i] = lx * csa - ly * sna + ax;
        cay[i] = lx * sna + ly * csa + ay;
        float mx = SX[i] * bdx, my = SY[i] * bdy;
        cbx[i] = mx * csb - my * snb + bx;
        cby[i] = mx * snb + my * csb + by;
    }

    // ---- pass 1: validity mask + masked centroid sums, exact slot order ----
    unsigned vmask = 0u;
    float sx = 0.0f, sy = 0.0f;
#pragma unroll
    for (int i = 0; i < 4; ++i) {
        bool v = pt_in_box(cax[i], cay[i], bx, by, bdx, bdy, csb, snb);
        vmask |= v ? (1u << i) : 0u;
        sx += v ? cax[i] : 0.0f;
        sy += v ? cay[i] : 0.0f;
    }
#pragma unroll
    for (int i = 0; i < 4; ++i) {
        bool v = pt_in_box(cbx[i], cby[i], ax, ay, adx, ady, csa, sna);
        vmask |= v ? (1u << (4 + i)) : 0u;
        sx += v ? cbx[i] : 0.0f;
        sy += v ? cby[i] : 0.0f;
    }
#pragma unroll
    for (int i = 0; i < 4; ++i) {
        float a0x = cax[i], a0y = cay[i];
        float d1x = cax[(i + 1) & 3] - a0x, d1y = cay[(i + 1) & 3] - a0y;
#pragma unroll
        for (int j = 0; j < 4; ++j) {
            int s = 8 + i * 4 + j;
            float b0x = cbx[j], b0y = cby[j];
            float d2x = cbx[(j + 1) & 3] - b0x, d2y = cby[(j + 1) & 3] - b0y;
            float r0x = b0x - a0x, r0y = b0y - a0y;
            float den = d1x * d2y - d1y * d2x;
            bool nz = fabsf(den) > 1e-8f;
            float sden = nz ? den : 1.0f;
            float t = (r0x * d2y - r0y * d2x) / sden;
            float u = (r0x * d1y - r0y * d1x) / sden;
            bool ok = nz && t >= 0.0f && t <= 1.0f && u >= 0.0f && u <= 1.0f;
            float ipx = a0x + t * d1x;
            float ipy = a0y + t * d1y;
            vmask |= ok ? (1u << s) : 0u;
            sx += ok ? ipx : 0.0f;
            sy += ok ? ipy : 0.0f;
        }
    }
    int kc = __popc(vmask);
    if (kc < 3) return 0.0f;
    float ctrx = sx / (float)kc, ctry = sy / (float)kc;

    // ---- pass 2: centered coords + sortable angle keys (recompute pts) ----
    float cx24[24], cy24[24];
    unsigned h[24];
#pragma unroll
    for (int i = 0; i < 4; ++i) {
        {
            bool v = (vmask >> i) & 1u;
            float cx = v ? cax[i] - ctrx : 0.0f;
            float cy = v ? cay[i] - ctry : 0.0f;
            cx24[i] = cx; cy24[i] = cy;
            h[i] = sortbits(v ? atan2f(cy, cx) : 1e9f);
        }
        {
            bool v = (vmask >> (4 + i)) & 1u;
            float cx = v ? cbx[i] - ctrx : 0.0f;
            float cy = v ? cby[i] - ctry : 0.0f;
            cx24[4 + i] = cx; cy24[4 + i] = cy;
            h[4 + i] = sortbits(v ? atan2f(cy, cx) : 1e9f);
        }
    }
#pragma unroll
    for (int i = 0; i < 4; ++i) {
        float a0x = cax[i], a0y = cay[i];
        float d1x = cax[(i + 1) & 3] - a0x, d1y = cay[(i + 1) & 3] - a0y;
#pragma unroll
        for (int j = 0; j < 4; ++j) {
            int s = 8 + i * 4 + j;
            float b0x = cbx[j], b0y = cby[j];
            float d2x = cbx[(j + 1) & 3] - b0x, d2y = cby[(j + 1) & 3] - b0y;
            float r0x = b0x - a0x, r0y = b0y - a0y;
            float den = d1x * d2y - d1y * d2x;
            bool nz = fabsf(den) > 1e-8f;
            float sden = nz ? den : 1.0f;
            float t = (r0x * d2y - r0y * d2x) / sden;
            bool v = (vmask >> s) & 1u;
            float ipx = a0x + t * d1x;
            float ipy = a0y + t * d1y;
            float cx = v ? ipx - ctrx : 0.0f;
            float cy = v ? ipy - ctry : 0.0f;
            cx24[s] = cx; cy24[s] = cy;
            h[s] = sortbits(v ? atan2f(cy, cx) : 1e9f);
        }
    }

    // ---- ranks: stable argsort position of each slot (276 compares) ----
    int rk[24];
#pragma unroll
    for (int s = 0; s < 24; ++s) rk[s] = 0;
#pragma unroll
    for (int s = 0; s < 24; ++s) {
#pragma unroll
        for (int t = s + 1; t < 24; ++t) {
            bool a = h[s] <= h[t];  // s precedes t (slot tiebreak: s<t)
            rk[t] += a ? 1 : 0;
            rk[s] += a ? 0 : 1;
        }
    }

    // ---- streaming position-order reconstruction + exact shoelace ----
    float acc = 0.0f;
    float fx = 0.0f, fy = 0.0f, lx = 0.0f, ly = 0.0f;
    float pxp = 0.0f, pyp = 0.0f;
#pragma unroll
    for (int p = 0; p < 24; ++p) {
        float X = 0.0f, Y = 0.0f;
#pragma unroll
        for (int s = 0; s < 24; ++s) {
            bool m = (rk[s] == p);
            X = m ? cx24[s] : X;
            Y = m ? cy24[s] : Y;
        }
        if (p == 0) {
            fx = X; fy = Y;
        } else {
            float cr = pxp * Y - pyp * X;
            acc += (p < kc) ? cr : 0.0f;  // term i=p-1, mask i+1<kc
        }
        bool e = (p == kc - 1);
        lx = e ? X : lx;
        ly = e ? Y : ly;
        pxp = X; pyp = Y;
    }
    acc += lx * fy - ly * fx;  // wrap term cross(p[kc-1], p[0])
    return 0.5f * fabsf(acc);
}

// ---------------------------------------------------------------------------
// prep2
// ---------------------------------------------------------------------------
__global__ __launch_bounds__(1024) void prep2_kernel(
        const float* __restrict__ labels, const float* __restrict__ cls,
        const float* __restrict__ gt, const float* __restrict__ pred,
        float* __restrict__ out, int* __restrict__ order,
        float* __restrict__ sbox, float4* __restrict__ circ_s,
        float4* __restrict__ circ_g, float4* __restrict__ circ_p,
        u64* __restrict__ sup, u64* __restrict__ rowmax,
        unsigned int* __restrict__ cnt) {
    int tid = threadIdx.x;
    float lab = labels[tid];
    float sig = 1.0f / (1.0f + expf(-cls[tid]));
    out[tid] = (sig > 0.55f && lab > 0.55f) ? 1.0f : 0.0f;
    out[NB + tid] = lab;

#pragma unroll
    for (int t = 0; t < 16; ++t) sup[tid * 16 + t] = 0ULL;
    rowmax[tid] = 1023ULL;  // pack(iou=0.0f, j=0)
    if (tid < 2) cnt[tid] = 0u;

    {
        float gx = gt[tid * 8 + 0], gy = gt[tid * 8 + 1];
        float gdx = gt[tid * 8 + 3], gdy = gt[tid * 8 + 4];
        circ_g[tid] = make_float4(gx, gy, 0.5f * sqrtf(gdx * gdx + gdy * gdy), 0.0f);
        float px = pred[tid * 7 + 0], py = pred[tid * 7 + 1];
        float pdx = pred[tid * 7 + 3], pdy = pred[tid * 7 + 4];
        circ_p[tid] = make_float4(px, py, 0.5f * sqrtf(pdx * pdx + pdy * pdy), 0.0f);
    }

    __shared__ float key_s[NB];
    __shared__ int idx_s[NB];
    float k = lab;
    int id = tid;
    for (int ksz = 2; ksz <= NB; ksz <<= 1) {
        for (int j = ksz >> 1; j > 0; j >>= 1) {
            bool dir_asc = (tid & ksz) == 0;
            float ok; int oi;
            if (j >= 64) {
                key_s[tid] = k; idx_s[tid] = id;
                __syncthreads();
                ok = key_s[tid ^ j]; oi = idx_s[tid ^ j];
                __syncthreads();
            } else {
                ok = __shfl_xor(k, j, 64);
                oi = __shfl_xor(id, j, 64);
            }
            bool isLow = (tid & j) == 0;
            bool pre = (k > ok) || (k == ok && id < oi);
            bool wantMine = (pre == (isLow == dir_asc));
            if (!wantMine) { k = ok; id = oi; }
        }
    }
    order[tid] = id;
    const float* g = &gt[id * 8];
#pragma unroll
    for (int c = 0; c < 7; ++c) sbox[tid * 8 + c] = g[c];
    sbox[tid * 8 + 7] = 0.0f;
    float sdx = g[3], sdy = g[4];
    circ_s[tid] = make_float4(g[0], g[1], 0.5f * sqrtf(sdx * sdx + sdy * sdy), 0.0f);
}

// ---------------------------------------------------------------------------
// cand3: one wave/block, wave-private LDS buffer (2048 = worst case pairs
// per block), ballot count in registers, one global atomicAdd per block.
// mode 0: gt x gt (sorted, j>i). mode 1: pred x gt with sampled[j] filter.
// ---------------------------------------------------------------------------
#define CB3 512

__global__ __launch_bounds__(64) void cand3_kernel(
        const float4* __restrict__ ca, const float4* __restrict__ cb,
        const int* __restrict__ sampled, int mode,
        unsigned int* __restrict__ list, unsigned int* __restrict__ cnt) {
    __shared__ unsigned int buf[2048];
    int lane = threadIdx.x;
    unsigned int nloc = 0;  // wave-uniform
    const unsigned int stride = CB3 * 64u;  // 32768
    unsigned int t = blockIdx.x * 64u + lane;
#pragma unroll
    for (unsigned int r = 0; r < 32; ++r, t += stride) {
        int i = (int)(t >> 10), j = (int)(t & 1023u);
        bool q = (mode == 0) ? (j > i) : (sampled[j] != 0);
        if (q) {
            float4 A = ca[i], B = cb[j];
            float dx = A.x - B.x, dy = A.y - B.y;
            float lim = A.z + B.z + 1e-3f;
            q = (dx * dx + dy * dy) <= lim * lim;
        }
        u64 m = __ballot(q ? 1 : 0);
        if (q) {
            unsigned int pos =
                nloc + (unsigned int)__popcll(m & ((1ULL << lane) - 1ULL));
            buf[pos] = (unsigned int)((i << 10) | j);
        }
        nloc += (unsigned int)__popcll(m);
    }
    __syncthreads();
    unsigned int base = 0;
    if (lane == 0 && nloc) base = atomicAdd(cnt, nloc);
    base = (unsigned int)__shfl((int)base, 0, 64);
    for (unsigned int s = lane; s < nloc; s += 64u) {
        unsigned int p = base + s;
        if (p < CAP) list[p] = buf[s];
    }
}

// ---------------------------------------------------------------------------
// evalA: exact rotated IoU on listA -> suppression bits. 1-wave blocks.
// ---------------------------------------------------------------------------
__global__ __launch_bounds__(64, 1) void evalA_kernel(
        const float* __restrict__ sbox, const unsigned int* __restrict__ list,
        const unsigned int* __restrict__ cnt, u64* __restrict__ sup) {
    unsigned int n = min(cnt[0], CAP);
    for (unsigned int t = blockIdx.x * 64 + threadIdx.x; t < n;
         t += gridDim.x * 64) {
        unsigned int p = list[t];
        int i = p >> 10, j = p & 1023;
        const float* A = &sbox[i * 8];
        const float* B = &sbox[j * 8];
        float inter = rect_inter_area(A[0], A[1], A[3], A[4], A[6],
                                      B[0], B[1], B[3], B[4], B[6]);
        float iou = inter / fmaxf(A[3] * A[4] + B[3] * B[4] - inter, 1e-8f);
        if (iou > 0.1f)
            atomicOr(&sup[i * 16 + (j >> 6)], 1ULL << (j & 63));
    }
}

// ---------------------------------------------------------------------------
// nms_seq5: greedy NMS, one wave. Lane b holds row (W*64+b) in registers.
//   per word W: one OR butterfly (cross-word suppression), LDS broadcast of
//   the 64 intra-word row-words, register prefetch of the next word-block's
//   rows (overlaps the chain), 64-step VALU cndmask chain, local acc update.
// ---------------------------------------------------------------------------
__global__ __launch_bounds__(64, 1) void nms_seq5_kernel(
        const u64* __restrict__ sup, const int* __restrict__ order,
        int* __restrict__ sampled) {
    __shared__ u64 bc[64];
    int lane = threadIdx.x;
    u64 kw[16];
    u64 acc[16];
    u64 row[16];
#pragma unroll
    for (int t = 0; t < 16; ++t) acc[t] = 0ULL;
#pragma unroll
    for (int t = 0; t < 16; ++t)
        row[t] = sup[(size_t)lane * 16 + t];  // rows of word-block 0

#pragma unroll
    for (int W = 0; W < 16; ++W) {
        // 1. cross-word suppression for word W (one butterfly over acc[W])
        u64 v = acc[W];
#pragma unroll
        for (int off = 32; off > 0; off >>= 1) v |= __shfl_xor(v, off, 64);
        u64 kwW = ~v;

        // 2. broadcast intra-word row-words
        bc[lane] = row[W];
        __syncthreads();

        // 2b. prefetch next word-block's rows (overlaps the chain below)
        u64 rowN[16];
#pragma unroll
        for (int t = 0; t < 16; ++t) rowN[t] = 0ULL;
        if (W < 15) {
#pragma unroll
            for (int t = 0; t < 16; ++t)
                if (t >= W + 1)
                    rowN[t] = sup[(size_t)((W + 1) * 64 + lane) * 16 + t];
        }

        // 3. intra-word greedy: pure-VALU cndmask chain (row bits are j>i
        //    only, so bc[b] never clears bits <= b)
#pragma unroll
        for (int b = 0; b < 64; ++b) {
            bool kb = (kwW >> b) & 1ULL;
            kwW &= kb ? ~bc[b] : ~0ULL;
        }
        kw[W] = kwW;

        // 4. kept lanes accumulate their row into future words (local only)
        bool me = (kwW >> lane) & 1ULL;
#pragma unroll
        for (int t = W + 1; t < 16; ++t) acc[t] |= me ? row[t] : 0ULL;

        __syncthreads();  // protect bc before next iteration's overwrite
#pragma unroll
        for (int t = 0; t < 16; ++t) row[t] = rowN[t];
    }

#pragma unroll
    for (int t = 0; t < 16; ++t) {
        int idx = t * 64 + lane;
        int bit = (int)((kw[t] >> lane) & 1ULL);
        sampled[order[idx]] = bit;
    }
}

// ---------------------------------------------------------------------------
// evalB: exact IoU3D on listB; packed (iou, first-idx) u64 atomicMax.
// ---------------------------------------------------------------------------
__global__ __launch_bounds__(64, 1) void evalB_kernel(
        const float* __restrict__ pred, const float* __restrict__ gt,
        const unsigned int* __restrict__ list,
        const unsigned int* __restrict__ cnt, u64* __restrict__ rowmax) {
    unsigned int n = min(cnt[1], CAP);
    for (unsigned int t = blockIdx.x * 64 + threadIdx.x; t < n;
         t += gridDim.x * 64) {
        unsigned int p = list[CAP + t];
        int i = p >> 10, j = p & 1023;
        float Ax = pred[i * 7 + 0], Ay = pred[i * 7 + 1], Az = pred[i * 7 + 2];
        float Adx = pred[i * 7 + 3], Ady = pred[i * 7 + 4], Adz = pred[i * 7 + 5];
        float Ar = pred[i * 7 + 6];
        float Bx = gt[j * 8 + 0], By = gt[j * 8 + 1], Bz = gt[j * 8 + 2];
        float Bdx = gt[j * 8 + 3], Bdy = gt[j * 8 + 4], Bdz = gt[j * 8 + 5];
        float Br = gt[j * 8 + 6];
        float inter = rect_inter_area(Ax, Ay, Adx, Ady, Ar,
                                      Bx, By, Bdx, Bdy, Br);
        float amax = Az + Adz * 0.5f, amin = Az - Adz * 0.5f;
        float bmax = Bz + Bdz * 0.5f, bmin = Bz - Bdz * 0.5f;
        float oh = fmaxf(fminf(amax, bmax) - fmaxf(amin, bmin), 0.0f);
        float inter3d = inter * oh;
        float va = Adx * Ady * Adz, vb = Bdx * Bdy * Bdz;
        float iou = inter3d / fmaxf(va + vb - inter3d, 1e-8f);
        u64 pk = (((u64)__float_as_uint(iou)) << 32) | (u64)(1023 - j);
        atomicMax(&rowmax[i], pk);
    }
}

__global__ __launch_bounds__(256) void fin_kernel(
        const u64* __restrict__ rowmax, float* __restrict__ out) {
    int i = blockIdx.x * 256 + threadIdx.x;
    u64 v = rowmax[i];
    float fv = __uint_as_float((unsigned int)(v >> 32));
    int j = 1023 - (int)(v & 0xFFFFFFFFULL);
    float mo = (fv > 0.75f) ? 1.0f : ((fv < 0.25f) ? 0.0f : fv);
    out[2 * NB + i] = mo;
    out[3 * NB + i] = (float)j;
}

// ---------------------------------------------------------------------------
// Fallback dense kernels (only if ws too small — never taken in practice).
// ---------------------------------------------------------------------------
__global__ __launch_bounds__(1024) void prep_kernel(
        const float* __restrict__ labels, const float* __restrict__ cls,
        const float* __restrict__ gt, float* __restrict__ out,
        int* __restrict__ order, float* __restrict__ sbox) {
    int tid = threadIdx.x;
    float lab = labels[tid];
    float sig = 1.0f / (1.0f + expf(-cls[tid]));
    out[tid] = (sig > 0.55f && lab > 0.55f) ? 1.0f : 0.0f;
    out[NB + tid] = lab;
    __shared__ float key[NB];
    __shared__ int idx[NB];
    key[tid] = lab;
    idx[tid] = tid;
    __syncthreads();
    for (int k = 2; k <= NB; k <<= 1) {
        for (int j = k >> 1; j > 0; j >>= 1) {
            int p = tid ^ j;
            if (p > tid) {
                float k1 = key[tid], k2 = key[p];
                int i1 = idx[tid], i2 = idx[p];
                bool lessPT = (k2 > k1) || (k2 == k1 && i2 < i1);
                bool asc = (tid & k) == 0;
                bool doswap = asc ? lessPT : !lessPT;
                if (doswap) {
                    key[tid] = k2; key[p] = k1;
                    idx[tid] = i2; idx[p] = i1;
                }
            }
            __syncthreads();
        }
    }
    int o = idx[tid];
    order[tid] = o;
#pragma unroll
    for (int c = 0; c < 7; ++c) sbox[tid * 8 + c] = gt[o * 8 + c];
    sbox[tid * 8 + 7] = 0.0f;
}

__global__ __launch_bounds__(256) void sup_kernel(
        const float* __restrict__ sbox, u64* __restrict__ sup) {
    int i = blockIdx.y;
    int j = blockIdx.x * 256 + threadIdx.x;
    int word = j >> 6;
    int lane = threadIdx.x & 63;
    int wmaxj = (word << 6) + 63;
    if (wmaxj <= i) {
        if (lane == 0) sup[i * 16 + word] = 0ULL;
        return;
    }
    bool pred = false;
    if (j > i) {
        const float* A = &sbox[i * 8];
        const float* B = &sbox[j * 8];
        float inter = rect_inter_area(A[0], A[1], A[3], A[4], A[6],
                                      B[0], B[1], B[3], B[4], B[6]);
        float iou = inter / fmaxf(A[3] * A[4] + B[3] * B[4] - inter, 1e-8f);
        pred = iou > 0.1f;
    }
    u64 m = __ballot(pred);
    if (lane == 0) sup[i * 16 + word] = m;
}

__global__ __launch_bounds__(256) void iou3d_row_kernel(
        const float* __restrict__ pred, const float* __restrict__ gt,
        const int* __restrict__ sampled, u64* __restrict__ rowmax) {
    int i = blockIdx.y;
    int j = blockIdx.x * 256 + threadIdx.x;
    float Ax = pred[i * 7 + 0], Ay = pred[i * 7 + 1], Az = pred[i * 7 + 2];
    float Adx = pred[i * 7 + 3], Ady = pred[i * 7 + 4], Adz = pred[i * 7 + 5];
    float Ar = pred[i * 7 + 6];
    float msk = sampled[j] ? 1.0f : 0.0f;
    float Bx = gt[j * 8 + 0] * msk, By = gt[j * 8 + 1] * msk;
    float Bz = gt[j * 8 + 2] * msk;
    float Bdx = gt[j * 8 + 3] * msk, Bdy = gt[j * 8 + 4] * msk;
    float Bdz = gt[j * 8 + 5] * msk;
    float Br = gt[j * 8 + 6] * msk;
    float inter = rect_inter_area(Ax, Ay, Adx, Ady, Ar, Bx, By, Bdx, Bdy, Br);
    float amax = Az + Adz * 0.5f, amin = Az - Adz * 0.5f;
    float bmax = Bz + Bdz * 0.5f, bmin = Bz - Bdz * 0.5f;
    float oh = fmaxf(fminf(amax, bmax) - fmaxf(amin, bmin), 0.0f);
    float inter3d = inter * oh;
    float va = Adx * Ady * Adz, vb = Bdx * Bdy * Bdz;
    float iou = inter3d / fmaxf(va + vb - inter3d, 1e-8f);
    u64 pk = (((u64)__float_as_uint(iou)) << 32) | (u64)(1023 - j);
    atomicMax(&rowmax[i], pk);
}

// ---------------------------------------------------------------------------
// Workspace layout:
//   [0,       4096)    int   order[1024]
//   [4096,    36864)   float sbox[1024*8]
//   [36864,   40960)   int   sampled[1024]
//   [40960,   172032)  u64   sup[1024*16]
//   [172032,  188416)  float4 circ_s[1024]
//   [188416,  204800)  float4 circ_g[1024]
//   [204800,  221184)  float4 circ_p[1024]
//   [221184,  229376)  u64   rowmax[1024]
//   [229376,  229440)  uint  cnt[2] (+pad)
//   [229440, +4*CAP)   uint  listA
//   [+4*CAP, +8*CAP)   uint  listB
// ---------------------------------------------------------------------------
extern "C" void kernel_launch(void* const* d_in, const int* in_sizes, int n_in,
                              void* d_out, int out_size, void* d_ws, size_t ws_size,
                              hipStream_t stream) {
    const float* labels = (const float*)d_in[0];
    const float* pred   = (const float*)d_in[1];
    const float* gt     = (const float*)d_in[2];
    const float* cls    = (const float*)d_in[3];
    float* out = (float*)d_out;

    char* ws = (char*)d_ws;
    int* order   = (int*)ws;
    float* sbox  = (float*)(ws + 4096);
    int* sampled = (int*)(ws + 36864);
    u64* sup     = (u64*)(ws + 40960);
    float4* circ_s = (float4*)(ws + 172032);
    float4* circ_g = (float4*)(ws + 188416);
    float4* circ_p = (float4*)(ws + 204800);
    u64* rowmax  = (u64*)(ws + 221184);
    unsigned int* cnt  = (unsigned int*)(ws + 229376);
    unsigned int* list = (unsigned int*)(ws + 229440);

    const size_t WS_NEEDED = 229440 + (size_t)8 * CAP;

    if (ws_size >= WS_NEEDED) {
        prep2_kernel<<<1, 1024, 0, stream>>>(labels, cls, gt, pred, out, order,
                                             sbox, circ_s, circ_g, circ_p, sup,
                                             rowmax, cnt);
        cand3_kernel<<<CB3, 64, 0, stream>>>(circ_s, circ_s, sampled, 0,
                                             list, &cnt[0]);
        evalA_kernel<<<256, 64, 0, stream>>>(sbox, list, cnt, sup);
        nms_seq5_kernel<<<1, 64, 0, stream>>>(sup, order, sampled);
        cand3_kernel<<<CB3, 64, 0, stream>>>(circ_p, circ_g, sampled, 1,
                                             list + CAP, &cnt[1]);
        evalB_kernel<<<256, 64, 0, stream>>>(pred, gt, list, cnt, rowmax);
        fin_kernel<<<4, 256, 0, stream>>>(rowmax, out);
    } else {
        prep_kernel<<<1, 1024, 0, stream>>>(labels, cls, gt, out, order, sbox);
        sup_kernel<<<dim3(4, 1024), 256, 0, stream>>>(sbox, sup);
        nms_seq5_kernel<<<1, 64, 0, stream>>>(sup, order, sampled);
        iou3d_row_kernel<<<dim3(4, 1024), 256, 0, stream>>>(pred, gt, sampled,
                                                            rowmax);
        fin_kernel<<<4, 256, 0, stream>>>(rowmax, out);
    }
}